// Round 1
// baseline (653.717 us; speedup 1.0000x reference)
//
#include <hip/hip_runtime.h>
#include <hip/hip_bf16.h>

#define N_ATOMS 10000
#define N_PAIR  100000
#define F_DIM   128
#define N_HEAD  4
#define FH      32
#define N_DEG   3
#define M_TOT   15
#define K_RBF   32
#define R_OUT   (N_ATOMS * M_TOT)   // 150000 rows in the output GEMM

__device__ __forceinline__ float sspf(float v) {
    // softplus(v) - log(2), stable form matching jax.nn.softplus
    float sp = fmaxf(v, 0.f) + log1pf(expf(-fabsf(v)));
    return sp - 0.69314718055994531f;
}

// ---------------- Kernel 1: x_f = x@W_in + b_in ; Q,K per (d,h) ----------------
// 8 atoms per block, 256 threads.
__global__ __launch_bounds__(256) void k_atom(
    const float* __restrict__ x, const float* __restrict__ W_in,
    const float* __restrict__ b_in, const float* __restrict__ W_Q,
    const float* __restrict__ W_K, float* __restrict__ xh,
    float* __restrict__ Q, float* __restrict__ K)
{
    __shared__ float xs[8][128];
    __shared__ float xf[8][128];
    int a0 = blockIdx.x * 8;
    int t = threadIdx.x;

    #pragma unroll
    for (int r = 0; r < 4; ++r) {
        int idx = t + 256 * r;
        int aa = idx >> 7, f = idx & 127;
        xs[aa][f] = x[(a0 + aa) * 128 + f];
    }
    __syncthreads();

    #pragma unroll
    for (int r = 0; r < 4; ++r) {
        int idx = t + 256 * r;
        int aa = idx >> 7, f = idx & 127;
        float acc = b_in[f];
        for (int k2 = 0; k2 < 128; ++k2)
            acc = fmaf(xs[aa][k2], W_in[k2 * 128 + f], acc);
        xf[aa][f] = acc;
        xh[(a0 + aa) * 128 + f] = acc;
    }
    __syncthreads();

    // Q[n,d,h,i] = sum_j W_Q[d,h,i,j] * xf[n, h*32+j]; 8*3*128 = 3072 outputs each
    #pragma unroll
    for (int r = 0; r < 12; ++r) {
        int idx = t + 256 * r;          // 0..3071
        int aa = idx / 384;
        int rem = idx % 384;            // d*128 + h*32 + i
        int d = rem >> 7;
        int hi2 = rem & 127;
        int h = hi2 >> 5, i = hi2 & 31;
        const float* wq = W_Q + ((d * 4 + h) * 32 + i) * 32;
        const float* wk = W_K + ((d * 4 + h) * 32 + i) * 32;
        const float* xv = &xf[aa][h * 32];
        float q = 0.f, kk = 0.f;
        #pragma unroll
        for (int j = 0; j < 32; ++j) {
            q  = fmaf(wq[j], xv[j], q);
            kk = fmaf(wk[j], xv[j], kk);
        }
        Q[(a0 + aa) * 384 + rem] = q;
        K[(a0 + aa) * 384 + rem] = kk;
    }
}

// ---------------- Kernel 2: filter net + alpha ----------------
// 16 pairs per block, 256 threads.
__global__ __launch_bounds__(256) void k_pair(
    const float* __restrict__ rbf, const float* __restrict__ phi,
    const float* __restrict__ mask, const int* __restrict__ idx_i,
    const int* __restrict__ idx_j, const float* __restrict__ W_f1,
    const float* __restrict__ b_f1, const float* __restrict__ W_f2,
    const float* __restrict__ b_f2, const float* __restrict__ Q,
    const float* __restrict__ K, float* __restrict__ alpha)
{
    __shared__ float rbf_s[16][33];
    __shared__ float h1_s[16][33];
    __shared__ float wij_s[16][384];
    int p0 = blockIdx.x * 16;
    int t = threadIdx.x;

    #pragma unroll
    for (int r = 0; r < 2; ++r) {
        int idx = t + 256 * r;
        int pp = idx >> 5, l = idx & 31;
        rbf_s[pp][l] = rbf[(p0 + pp) * 32 + l];
    }
    __syncthreads();

    #pragma unroll
    for (int r = 0; r < 2; ++r) {
        int idx = t + 256 * r;
        int pp = idx >> 5, l = idx & 31;
        float acc = b_f1[l];
        #pragma unroll
        for (int k2 = 0; k2 < 32; ++k2)
            acc = fmaf(rbf_s[pp][k2], W_f1[k2 * 32 + l], acc);
        h1_s[pp][l] = sspf(acc);
    }
    __syncthreads();

    // W_ij: 16 pairs * 384 = 6144 outputs
    #pragma unroll
    for (int r = 0; r < 24; ++r) {
        int idx = t + 256 * r;
        int pp = idx / 384;
        int e = idx % 384;              // d*128 + h*32 + f
        float acc = b_f2[e];
        #pragma unroll
        for (int k2 = 0; k2 < 32; ++k2)
            acc = fmaf(h1_s[pp][k2], W_f2[k2 * 384 + e], acc);
        wij_s[pp][e] = acc * phi[p0 + pp];
    }
    __syncthreads();

    // alpha[p,d,h] = sum_f Qi*Kj*Wij * mask^2 / sqrt(FH)
    if (t < 192) {
        int pp = t / 12;
        int dh = t % 12;
        int d = dh >> 2, h = dh & 3;
        int p = p0 + pp;
        int i = idx_i[p], j = idx_j[p];
        const float* qp = Q + i * 384 + d * 128 + h * 32;
        const float* kp = K + j * 384 + d * 128 + h * 32;
        const float* wp = &wij_s[pp][d * 128 + h * 32];
        float acc = 0.f;
        #pragma unroll
        for (int f = 0; f < 32; ++f)
            acc = fmaf(qp[f] * kp[f], wp[f], acc);
        float m = mask[p];
        alpha[p * 12 + dh] = acc * m * m * 0.17677669529663687f; // 1/sqrt(32)
    }
}

__device__ __forceinline__ int lower_bound_i(const int* __restrict__ arr, int n, int val) {
    int lo = 0, hi = n;
    while (lo < hi) {
        int mid = (lo + hi) >> 1;
        if (arr[mid] < val) lo = mid + 1; else hi = mid;
    }
    return lo;
}

// ---------------- Kernel 3: segment aggregation (idx_i sorted) ----------------
// one block (128 threads) per atom; f = tid; 15 accumulators in registers.
__global__ __launch_bounds__(128) void k_agg(
    const float* __restrict__ xh, const float* __restrict__ alpha,
    const float* __restrict__ sph, const int* __restrict__ idx_i,
    const int* __restrict__ idx_j, const float* __restrict__ mask,
    float* __restrict__ agg)
{
    int a = blockIdx.x;
    int t = threadIdx.x;
    int h = t >> 5;
    int lo = lower_bound_i(idx_i, N_PAIR, a);
    int hi = lower_bound_i(idx_i, N_PAIR, a + 1);

    float acc[15];
    #pragma unroll
    for (int m = 0; m < 15; ++m) acc[m] = 0.f;

    for (int p = lo; p < hi; ++p) {
        int j = idx_j[p];
        float mk = mask[p];
        float xj = xh[j * 128 + t] * mk;
        float a0v = alpha[p * 12 + h];
        float a1v = alpha[p * 12 + 4 + h];
        float a2v = alpha[p * 12 + 8 + h];
        const float* sp = sph + p * 15;
        #pragma unroll
        for (int m = 0; m < 15; ++m) {
            float al = (m < 3) ? a0v : ((m < 8) ? a1v : a2v);
            acc[m] = fmaf(sp[m] * al, xj, acc[m]);
        }
    }
    #pragma unroll
    for (int m = 0; m < 15; ++m)
        agg[(a * 15 + m) * 128 + t] = acc[m];
}

// ---------------- Kernel 4: out = agg @ W_out + b_out, in-place on d_out ------
// 128x128 output tile per block, 256 threads, 4x4+offset-64 micro-tile.
__global__ __launch_bounds__(256) void k_out(
    float* __restrict__ C, const float* __restrict__ W_out,
    const float* __restrict__ b_out)
{
    __shared__ float As[32][132];   // [k][row], padded
    __shared__ float Bs[32][132];   // [k][col], padded
    int r0 = blockIdx.x * 128;
    int t = threadIdx.x;
    int ty = t >> 4, tx = t & 15;

    float acc[8][8];
    #pragma unroll
    for (int i = 0; i < 8; ++i)
        #pragma unroll
        for (int j = 0; j < 8; ++j) acc[i][j] = 0.f;

    for (int k0 = 0; k0 < 128; k0 += 32) {
        // A tile: 128 rows x 32 k, transposed into As[k][row]
        #pragma unroll
        for (int r = 0; r < 16; ++r) {
            int idx = t + 256 * r;
            int row = idx >> 5, kk = idx & 31;
            int grow = r0 + row;
            As[kk][row] = (grow < R_OUT) ? C[grow * 128 + k0 + kk] : 0.f;
        }
        // B tile: 32 k x 128 cols
        #pragma unroll
        for (int r = 0; r < 16; ++r) {
            int idx = t + 256 * r;
            int kk = idx >> 7, c = idx & 127;
            Bs[kk][c] = W_out[(k0 + kk) * 128 + c];
        }
        __syncthreads();

        #pragma unroll
        for (int kk = 0; kk < 32; ++kk) {
            float a[8], b[8];
            *(float4*)&a[0] = *(const float4*)&As[kk][ty * 4];
            *(float4*)&a[4] = *(const float4*)&As[kk][64 + ty * 4];
            *(float4*)&b[0] = *(const float4*)&Bs[kk][tx * 4];
            *(float4*)&b[4] = *(const float4*)&Bs[kk][64 + tx * 4];
            #pragma unroll
            for (int i = 0; i < 8; ++i)
                #pragma unroll
                for (int j = 0; j < 8; ++j)
                    acc[i][j] = fmaf(a[i], b[j], acc[i][j]);
        }
        __syncthreads();
    }

    float bj[8];
    #pragma unroll
    for (int j = 0; j < 4; ++j) { bj[j] = b_out[tx * 4 + j]; bj[4 + j] = b_out[64 + tx * 4 + j]; }

    #pragma unroll
    for (int i = 0; i < 8; ++i) {
        int row = r0 + ((i < 4) ? (ty * 4 + i) : (64 + ty * 4 + (i - 4)));
        if (row < R_OUT) {
            float4 v0, v1;
            v0.x = acc[i][0] + bj[0]; v0.y = acc[i][1] + bj[1];
            v0.z = acc[i][2] + bj[2]; v0.w = acc[i][3] + bj[3];
            v1.x = acc[i][4] + bj[4]; v1.y = acc[i][5] + bj[5];
            v1.z = acc[i][6] + bj[6]; v1.w = acc[i][7] + bj[7];
            *(float4*)&C[row * 128 + tx * 4] = v0;
            *(float4*)&C[row * 128 + 64 + tx * 4] = v1;
        }
    }
}

extern "C" void kernel_launch(void* const* d_in, const int* in_sizes, int n_in,
                              void* d_out, int out_size, void* d_ws, size_t ws_size,
                              hipStream_t stream) {
    const float* x        = (const float*)d_in[0];
    const float* rbf_ij   = (const float*)d_in[1];
    const float* sph_ij   = (const float*)d_in[2];
    const float* phi_r    = (const float*)d_in[3];
    const int*   idx_i    = (const int*)d_in[4];
    const int*   idx_j    = (const int*)d_in[5];
    const float* pmask    = (const float*)d_in[6];
    const float* W_Q      = (const float*)d_in[7];
    const float* W_K      = (const float*)d_in[8];
    const float* W_in     = (const float*)d_in[9];
    const float* b_in     = (const float*)d_in[10];
    const float* W_f1     = (const float*)d_in[11];
    const float* b_f1     = (const float*)d_in[12];
    const float* W_f2     = (const float*)d_in[13];
    const float* b_f2     = (const float*)d_in[14];
    const float* W_out    = (const float*)d_in[15];
    const float* b_out    = (const float*)d_in[16];
    float* out = (float*)d_out;

    // workspace layout (floats)
    float* ws    = (float*)d_ws;
    float* xh    = ws;                                   // 10000*128   = 1,280,000
    float* Qbuf  = xh + N_ATOMS * F_DIM;                 // 10000*384   = 3,840,000
    float* Kbuf  = Qbuf + N_ATOMS * 384;                 // 10000*384   = 3,840,000
    float* alpha = Kbuf + N_ATOMS * 384;                 // 100000*12   = 1,200,000

    k_atom<<<N_ATOMS / 8, 256, 0, stream>>>(x, W_in, b_in, W_Q, W_K, xh, Qbuf, Kbuf);
    k_pair<<<N_PAIR / 16, 256, 0, stream>>>(rbf_ij, phi_r, pmask, idx_i, idx_j,
                                            W_f1, b_f1, W_f2, b_f2, Qbuf, Kbuf, alpha);
    k_agg<<<N_ATOMS, 128, 0, stream>>>(xh, alpha, sph_ij, idx_i, idx_j, pmask, out);
    k_out<<<(R_OUT + 127) / 128, 256, 0, stream>>>(out, W_out, b_out);
}

// Round 2
// 506.970 us; speedup vs baseline: 1.2895x; 1.2895x over previous
//
#include <hip/hip_runtime.h>
#include <hip/hip_bf16.h>

#define N_ATOMS 10000
#define N_PAIR  100000
#define F_DIM   128
#define N_HEAD  4
#define FH      32
#define N_DEG   3
#define M_TOT   15
#define K_RBF   32
#define R_OUT   (N_ATOMS * M_TOT)   // 150000 rows in the output GEMM

__device__ __forceinline__ float sspf(float v) {
    // softplus(v) - log(2), stable form matching jax.nn.softplus
    float sp = fmaxf(v, 0.f) + log1pf(expf(-fabsf(v)));
    return sp - 0.69314718055994531f;
}

// ---------------- Generic 128-col GEMM: C[rows,128] = A[rows,128]@B[128,128]+bias
// 128x128 tile per block, 256 threads, 8x8 micro-tile (split 4+4 at offset 64).
// Safe in-place when A == C (each block reads only its own 128 rows).
__global__ __launch_bounds__(256) void k_gemm128(
    const float* __restrict__ A, const float* __restrict__ B,
    const float* __restrict__ bias, float* __restrict__ C, int rows)
{
    __shared__ float As[32][132];   // [k][row], padded
    __shared__ float Bs[32][132];   // [k][col], padded
    int r0 = blockIdx.x * 128;
    int t = threadIdx.x;
    int ty = t >> 4, tx = t & 15;

    float acc[8][8];
    #pragma unroll
    for (int i = 0; i < 8; ++i)
        #pragma unroll
        for (int j = 0; j < 8; ++j) acc[i][j] = 0.f;

    for (int k0 = 0; k0 < 128; k0 += 32) {
        #pragma unroll
        for (int r = 0; r < 16; ++r) {
            int idx = t + 256 * r;
            int row = idx >> 5, kk = idx & 31;
            int grow = r0 + row;
            As[kk][row] = (grow < rows) ? A[grow * 128 + k0 + kk] : 0.f;
        }
        #pragma unroll
        for (int r = 0; r < 16; ++r) {
            int idx = t + 256 * r;
            int kk = idx >> 7, c = idx & 127;
            Bs[kk][c] = B[(k0 + kk) * 128 + c];
        }
        __syncthreads();

        #pragma unroll
        for (int kk = 0; kk < 32; ++kk) {
            float a[8], b[8];
            *(float4*)&a[0] = *(const float4*)&As[kk][ty * 4];
            *(float4*)&a[4] = *(const float4*)&As[kk][64 + ty * 4];
            *(float4*)&b[0] = *(const float4*)&Bs[kk][tx * 4];
            *(float4*)&b[4] = *(const float4*)&Bs[kk][64 + tx * 4];
            #pragma unroll
            for (int i = 0; i < 8; ++i)
                #pragma unroll
                for (int j = 0; j < 8; ++j)
                    acc[i][j] = fmaf(a[i], b[j], acc[i][j]);
        }
        __syncthreads();
    }

    float bj[8];
    #pragma unroll
    for (int j = 0; j < 4; ++j) { bj[j] = bias[tx * 4 + j]; bj[4 + j] = bias[64 + tx * 4 + j]; }

    #pragma unroll
    for (int i = 0; i < 8; ++i) {
        int row = r0 + ((i < 4) ? (ty * 4 + i) : (64 + ty * 4 + (i - 4)));
        if (row < rows) {
            float4 v0, v1;
            v0.x = acc[i][0] + bj[0]; v0.y = acc[i][1] + bj[1];
            v0.z = acc[i][2] + bj[2]; v0.w = acc[i][3] + bj[3];
            v1.x = acc[i][4] + bj[4]; v1.y = acc[i][5] + bj[5];
            v1.z = acc[i][6] + bj[6]; v1.w = acc[i][7] + bj[7];
            *(float4*)&C[row * 128 + tx * 4] = v0;
            *(float4*)&C[row * 128 + 64 + tx * 4] = v1;
        }
    }
}

// ---------------- Q/K projection: weights resident in registers -------------
// 384 threads = one per output column e = d*128 + h*32 + i. 64 atoms/block.
__global__ __launch_bounds__(384) void k_qk(
    const float* __restrict__ xh, const float* __restrict__ W_Q,
    const float* __restrict__ W_K, float* __restrict__ Q, float* __restrict__ K)
{
    __shared__ float xfs[32][128];
    int t = threadIdx.x;                 // == e
    int h = (t >> 5) & 3;
    float wq[32], wk[32];
    const float4* wqp = (const float4*)(W_Q + t * 32);   // ((d*4+h)*32+i)*32 == e*32
    const float4* wkp = (const float4*)(W_K + t * 32);
    #pragma unroll
    for (int j4 = 0; j4 < 8; ++j4) {
        float4 a = wqp[j4], b = wkp[j4];
        wq[4 * j4 + 0] = a.x; wq[4 * j4 + 1] = a.y; wq[4 * j4 + 2] = a.z; wq[4 * j4 + 3] = a.w;
        wk[4 * j4 + 0] = b.x; wk[4 * j4 + 1] = b.y; wk[4 * j4 + 2] = b.z; wk[4 * j4 + 3] = b.w;
    }
    int a0 = blockIdx.x * 64;
    for (int c = 0; c < 2; ++c) {
        int ab = a0 + c * 32;
        __syncthreads();
        for (int idx = t; idx < 4096; idx += 384) {
            int aa = idx >> 7, f = idx & 127;
            int ag = ab + aa;
            xfs[aa][f] = (ag < N_ATOMS) ? xh[ag * 128 + f] : 0.f;
        }
        __syncthreads();
        for (int aa = 0; aa < 32; ++aa) {
            int ag = ab + aa;
            if (ag >= N_ATOMS) break;
            const float4* xv = (const float4*)&xfs[aa][h * 32];
            float q0 = 0.f, q1 = 0.f, k0 = 0.f, k1 = 0.f;
            #pragma unroll
            for (int j4 = 0; j4 < 8; j4 += 2) {
                float4 x0 = xv[j4], x1 = xv[j4 + 1];
                q0 = fmaf(wq[4 * j4 + 0], x0.x, q0); q0 = fmaf(wq[4 * j4 + 1], x0.y, q0);
                q0 = fmaf(wq[4 * j4 + 2], x0.z, q0); q0 = fmaf(wq[4 * j4 + 3], x0.w, q0);
                q1 = fmaf(wq[4 * j4 + 4], x1.x, q1); q1 = fmaf(wq[4 * j4 + 5], x1.y, q1);
                q1 = fmaf(wq[4 * j4 + 6], x1.z, q1); q1 = fmaf(wq[4 * j4 + 7], x1.w, q1);
                k0 = fmaf(wk[4 * j4 + 0], x0.x, k0); k0 = fmaf(wk[4 * j4 + 1], x0.y, k0);
                k0 = fmaf(wk[4 * j4 + 2], x0.z, k0); k0 = fmaf(wk[4 * j4 + 3], x0.w, k0);
                k1 = fmaf(wk[4 * j4 + 4], x1.x, k1); k1 = fmaf(wk[4 * j4 + 5], x1.y, k1);
                k1 = fmaf(wk[4 * j4 + 6], x1.z, k1); k1 = fmaf(wk[4 * j4 + 7], x1.w, k1);
            }
            Q[ag * 384 + t] = q0 + q1;
            K[ag * 384 + t] = k0 + k1;
        }
    }
}

// ---------------- Pair kernel: filter net + alpha ---------------------------
// 384 threads = one per W_ij column e; W_f2 column in 32 registers; 64 pairs/block.
__global__ __launch_bounds__(384) void k_pair(
    const float* __restrict__ rbf, const float* __restrict__ phi,
    const float* __restrict__ mask, const int* __restrict__ idx_i,
    const int* __restrict__ idx_j, const float* __restrict__ W_f1,
    const float* __restrict__ b_f1, const float* __restrict__ W_f2,
    const float* __restrict__ b_f2, const float* __restrict__ Q,
    const float* __restrict__ K, float* __restrict__ alpha)
{
    __shared__ float wf1s[32][33];
    __shared__ float b1s[32];
    __shared__ float rbf_s[64][36];
    __shared__ float h1_s[64][36];
    __shared__ float phi_s[64];
    __shared__ float m_s[64];
    __shared__ int   i_s[64];
    __shared__ int   j_s[64];

    int t = threadIdx.x;                 // == e = d*128 + h*32 + f
    int p0 = blockIdx.x * 64;

    // W_f2 column -> 32 registers (coalesced per-k across threads)
    float wf2r[32];
    #pragma unroll
    for (int k = 0; k < 32; ++k) wf2r[k] = W_f2[k * 384 + t];
    float b2 = b_f2[t];

    // stage W_f1, b_f1, rbf tile, per-pair scalars
    for (int idx = t; idx < 1024; idx += 384) wf1s[idx >> 5][idx & 31] = W_f1[idx];
    if (t < 32) b1s[t] = b_f1[t];
    for (int idx = t; idx < 2048; idx += 384) {
        int pp = idx >> 5, l = idx & 31;
        int pg = p0 + pp;
        rbf_s[pp][l] = (pg < N_PAIR) ? rbf[pg * 32 + l] : 0.f;
    }
    if (t < 64) {
        int pg = p0 + t;
        bool v = pg < N_PAIR;
        phi_s[t] = v ? phi[pg] : 0.f;
        m_s[t]   = v ? mask[pg] : 0.f;
        i_s[t]   = v ? idx_i[pg] : 0;
        j_s[t]   = v ? idx_j[pg] : 0;
    }
    __syncthreads();

    // h1 = ssp(rbf @ W_f1 + b_f1)  (64 x 32 outputs)
    for (int idx = t; idx < 2048; idx += 384) {
        int pp = idx >> 5, l = idx & 31;
        float acc = b1s[l];
        #pragma unroll
        for (int k = 0; k < 32; ++k)
            acc = fmaf(rbf_s[pp][k], wf1s[k][l], acc);
        h1_s[pp][l] = sspf(acc);
    }
    __syncthreads();

    // per-pair: w = (h1 . wf2col + b2)*phi ; alpha = reduce_f(Qi*Kj*w)*m^2/sqrt(32)
    float qv = Q[i_s[0] * 384 + t];
    float kv = K[j_s[0] * 384 + t];
    for (int p = 0; p < 64; ++p) {
        float qn = 0.f, kn = 0.f;
        if (p < 63) {
            qn = Q[i_s[p + 1] * 384 + t];
            kn = K[j_s[p + 1] * 384 + t];
        }
        const float4* h4 = (const float4*)&h1_s[p][0];
        float w0 = b2, w1 = 0.f, w2 = 0.f, w3 = 0.f;
        #pragma unroll
        for (int k4 = 0; k4 < 8; k4 += 4) {
            float4 ha = h4[k4], hb = h4[k4 + 1], hc = h4[k4 + 2], hd = h4[k4 + 3];
            w0 = fmaf(ha.x, wf2r[4 * k4 + 0], w0);  w0 = fmaf(ha.y, wf2r[4 * k4 + 1], w0);
            w0 = fmaf(ha.z, wf2r[4 * k4 + 2], w0);  w0 = fmaf(ha.w, wf2r[4 * k4 + 3], w0);
            w1 = fmaf(hb.x, wf2r[4 * k4 + 4], w1);  w1 = fmaf(hb.y, wf2r[4 * k4 + 5], w1);
            w1 = fmaf(hb.z, wf2r[4 * k4 + 6], w1);  w1 = fmaf(hb.w, wf2r[4 * k4 + 7], w1);
            w2 = fmaf(hc.x, wf2r[4 * k4 + 8], w2);  w2 = fmaf(hc.y, wf2r[4 * k4 + 9], w2);
            w2 = fmaf(hc.z, wf2r[4 * k4 + 10], w2); w2 = fmaf(hc.w, wf2r[4 * k4 + 11], w2);
            w3 = fmaf(hd.x, wf2r[4 * k4 + 12], w3); w3 = fmaf(hd.y, wf2r[4 * k4 + 13], w3);
            w3 = fmaf(hd.z, wf2r[4 * k4 + 14], w3); w3 = fmaf(hd.w, wf2r[4 * k4 + 15], w3);
        }
        float w = ((w0 + w1) + (w2 + w3)) * phi_s[p];
        float part = qv * kv * w;
        #pragma unroll
        for (int off = 16; off >= 1; off >>= 1)
            part += __shfl_xor(part, off, 32);
        if ((t & 31) == 0) {
            int pg = p0 + p;
            if (pg < N_PAIR) {
                int d = t >> 7, h = (t >> 5) & 3;
                float m = m_s[p];
                alpha[pg * 12 + d * 4 + h] = part * m * m * 0.17677669529663687f;
            }
        }
        qv = qn; kv = kn;
    }
}

__device__ __forceinline__ int lower_bound_i(const int* __restrict__ arr, int n, int val) {
    int lo = 0, hi = n;
    while (lo < hi) {
        int mid = (lo + hi) >> 1;
        if (arr[mid] < val) lo = mid + 1; else hi = mid;
    }
    return lo;
}

// ---------------- Segment aggregation (idx_i sorted) ------------------------
__global__ __launch_bounds__(128) void k_agg(
    const float* __restrict__ xh, const float* __restrict__ alpha,
    const float* __restrict__ sph, const int* __restrict__ idx_i,
    const int* __restrict__ idx_j, const float* __restrict__ mask,
    float* __restrict__ agg)
{
    int a = blockIdx.x;
    int t = threadIdx.x;
    int h = t >> 5;
    int lo = lower_bound_i(idx_i, N_PAIR, a);
    int hi = lower_bound_i(idx_i, N_PAIR, a + 1);

    float acc[15];
    #pragma unroll
    for (int m = 0; m < 15; ++m) acc[m] = 0.f;

    for (int p = lo; p < hi; ++p) {
        int j = idx_j[p];
        float mk = mask[p];
        float xj = xh[j * 128 + t] * mk;
        float a0v = alpha[p * 12 + h];
        float a1v = alpha[p * 12 + 4 + h];
        float a2v = alpha[p * 12 + 8 + h];
        const float* sp = sph + p * 15;
        #pragma unroll
        for (int m = 0; m < 15; ++m) {
            float al = (m < 3) ? a0v : ((m < 8) ? a1v : a2v);
            acc[m] = fmaf(sp[m] * al, xj, acc[m]);
        }
    }
    #pragma unroll
    for (int m = 0; m < 15; ++m)
        agg[(a * 15 + m) * 128 + t] = acc[m];
}

extern "C" void kernel_launch(void* const* d_in, const int* in_sizes, int n_in,
                              void* d_out, int out_size, void* d_ws, size_t ws_size,
                              hipStream_t stream) {
    const float* x        = (const float*)d_in[0];
    const float* rbf_ij   = (const float*)d_in[1];
    const float* sph_ij   = (const float*)d_in[2];
    const float* phi_r    = (const float*)d_in[3];
    const int*   idx_i    = (const int*)d_in[4];
    const int*   idx_j    = (const int*)d_in[5];
    const float* pmask    = (const float*)d_in[6];
    const float* W_Q      = (const float*)d_in[7];
    const float* W_K      = (const float*)d_in[8];
    const float* W_in     = (const float*)d_in[9];
    const float* b_in     = (const float*)d_in[10];
    const float* W_f1     = (const float*)d_in[11];
    const float* b_f1     = (const float*)d_in[12];
    const float* W_f2     = (const float*)d_in[13];
    const float* b_f2     = (const float*)d_in[14];
    const float* W_out    = (const float*)d_in[15];
    const float* b_out    = (const float*)d_in[16];
    float* out = (float*)d_out;

    float* ws    = (float*)d_ws;
    float* xh    = ws;                                   // 10000*128
    float* Qbuf  = xh + N_ATOMS * F_DIM;                 // 10000*384
    float* Kbuf  = Qbuf + N_ATOMS * 384;                 // 10000*384
    float* alpha = Kbuf + N_ATOMS * 384;                 // 100000*12

    k_gemm128<<<(N_ATOMS + 127) / 128, 256, 0, stream>>>(x, W_in, b_in, xh, N_ATOMS);
    k_qk<<<(N_ATOMS + 63) / 64, 384, 0, stream>>>(xh, W_Q, W_K, Qbuf, Kbuf);
    k_pair<<<(N_PAIR + 63) / 64, 384, 0, stream>>>(rbf_ij, phi_r, pmask, idx_i, idx_j,
                                                   W_f1, b_f1, W_f2, b_f2, Qbuf, Kbuf, alpha);
    k_agg<<<N_ATOMS, 128, 0, stream>>>(xh, alpha, sph_ij, idx_i, idx_j, pmask, out);
    k_gemm128<<<(R_OUT + 127) / 128, 256, 0, stream>>>(out, W_out, b_out, out, R_OUT);
}

// Round 3
// 461.730 us; speedup vs baseline: 1.4158x; 1.0980x over previous
//
#include <hip/hip_runtime.h>
#include <hip/hip_bf16.h>

#define N_ATOMS 10000
#define N_PAIR  100000
#define F_DIM   128
#define N_HEAD  4
#define FH      32
#define N_DEG   3
#define M_TOT   15
#define K_RBF   32
#define R_OUT   (N_ATOMS * M_TOT)   // 150000 rows in the output GEMM

__device__ __forceinline__ float sspf(float v) {
    // softplus(v) - log(2), stable form matching jax.nn.softplus
    float sp = fmaxf(v, 0.f) + log1pf(expf(-fabsf(v)));
    return sp - 0.69314718055994531f;
}

// ---------------- Generic 128-col GEMM: C[rows,128] = A[rows,128]@B[128,128]+bias
__global__ __launch_bounds__(256) void k_gemm128(
    const float* __restrict__ A, const float* __restrict__ B,
    const float* __restrict__ bias, float* __restrict__ C, int rows)
{
    __shared__ float As[32][132];   // [k][row], padded
    __shared__ float Bs[32][132];   // [k][col], padded
    int r0 = blockIdx.x * 128;
    int t = threadIdx.x;
    int ty = t >> 4, tx = t & 15;

    float acc[8][8];
    #pragma unroll
    for (int i = 0; i < 8; ++i)
        #pragma unroll
        for (int j = 0; j < 8; ++j) acc[i][j] = 0.f;

    for (int k0 = 0; k0 < 128; k0 += 32) {
        #pragma unroll
        for (int r = 0; r < 16; ++r) {
            int idx = t + 256 * r;
            int row = idx >> 5, kk = idx & 31;
            int grow = r0 + row;
            As[kk][row] = (grow < rows) ? A[grow * 128 + k0 + kk] : 0.f;
        }
        #pragma unroll
        for (int r = 0; r < 16; ++r) {
            int idx = t + 256 * r;
            int kk = idx >> 7, c = idx & 127;
            Bs[kk][c] = B[(k0 + kk) * 128 + c];
        }
        __syncthreads();

        #pragma unroll
        for (int kk = 0; kk < 32; ++kk) {
            float a[8], b[8];
            *(float4*)&a[0] = *(const float4*)&As[kk][ty * 4];
            *(float4*)&a[4] = *(const float4*)&As[kk][64 + ty * 4];
            *(float4*)&b[0] = *(const float4*)&Bs[kk][tx * 4];
            *(float4*)&b[4] = *(const float4*)&Bs[kk][64 + tx * 4];
            #pragma unroll
            for (int i = 0; i < 8; ++i)
                #pragma unroll
                for (int j = 0; j < 8; ++j)
                    acc[i][j] = fmaf(a[i], b[j], acc[i][j]);
        }
        __syncthreads();
    }

    float bj[8];
    #pragma unroll
    for (int j = 0; j < 4; ++j) { bj[j] = bias[tx * 4 + j]; bj[4 + j] = bias[64 + tx * 4 + j]; }

    #pragma unroll
    for (int i = 0; i < 8; ++i) {
        int row = r0 + ((i < 4) ? (ty * 4 + i) : (64 + ty * 4 + (i - 4)));
        if (row < rows) {
            float4 v0, v1;
            v0.x = acc[i][0] + bj[0]; v0.y = acc[i][1] + bj[1];
            v0.z = acc[i][2] + bj[2]; v0.w = acc[i][3] + bj[3];
            v1.x = acc[i][4] + bj[4]; v1.y = acc[i][5] + bj[5];
            v1.z = acc[i][6] + bj[6]; v1.w = acc[i][7] + bj[7];
            *(float4*)&C[row * 128 + tx * 4] = v0;
            *(float4*)&C[row * 128 + 64 + tx * 4] = v1;
        }
    }
}

// ---------------- Q/K projection: weights resident in registers -------------
__global__ __launch_bounds__(384) void k_qk(
    const float* __restrict__ xh, const float* __restrict__ W_Q,
    const float* __restrict__ W_K, float* __restrict__ Q, float* __restrict__ K)
{
    __shared__ float xfs[32][128];
    int t = threadIdx.x;                 // == e
    int h = (t >> 5) & 3;
    float wq[32], wk[32];
    const float4* wqp = (const float4*)(W_Q + t * 32);
    const float4* wkp = (const float4*)(W_K + t * 32);
    #pragma unroll
    for (int j4 = 0; j4 < 8; ++j4) {
        float4 a = wqp[j4], b = wkp[j4];
        wq[4 * j4 + 0] = a.x; wq[4 * j4 + 1] = a.y; wq[4 * j4 + 2] = a.z; wq[4 * j4 + 3] = a.w;
        wk[4 * j4 + 0] = b.x; wk[4 * j4 + 1] = b.y; wk[4 * j4 + 2] = b.z; wk[4 * j4 + 3] = b.w;
    }
    int a0 = blockIdx.x * 64;
    for (int c = 0; c < 2; ++c) {
        int ab = a0 + c * 32;
        __syncthreads();
        for (int idx = t; idx < 4096; idx += 384) {
            int aa = idx >> 7, f = idx & 127;
            int ag = ab + aa;
            xfs[aa][f] = (ag < N_ATOMS) ? xh[ag * 128 + f] : 0.f;
        }
        __syncthreads();
        for (int aa = 0; aa < 32; ++aa) {
            int ag = ab + aa;
            if (ag >= N_ATOMS) break;
            const float4* xv = (const float4*)&xfs[aa][h * 32];
            float q0 = 0.f, q1 = 0.f, k0 = 0.f, k1 = 0.f;
            #pragma unroll
            for (int j4 = 0; j4 < 8; j4 += 2) {
                float4 x0 = xv[j4], x1 = xv[j4 + 1];
                q0 = fmaf(wq[4 * j4 + 0], x0.x, q0); q0 = fmaf(wq[4 * j4 + 1], x0.y, q0);
                q0 = fmaf(wq[4 * j4 + 2], x0.z, q0); q0 = fmaf(wq[4 * j4 + 3], x0.w, q0);
                q1 = fmaf(wq[4 * j4 + 4], x1.x, q1); q1 = fmaf(wq[4 * j4 + 5], x1.y, q1);
                q1 = fmaf(wq[4 * j4 + 6], x1.z, q1); q1 = fmaf(wq[4 * j4 + 7], x1.w, q1);
                k0 = fmaf(wk[4 * j4 + 0], x0.x, k0); k0 = fmaf(wk[4 * j4 + 1], x0.y, k0);
                k0 = fmaf(wk[4 * j4 + 2], x0.z, k0); k0 = fmaf(wk[4 * j4 + 3], x0.w, k0);
                k1 = fmaf(wk[4 * j4 + 4], x1.x, k1); k1 = fmaf(wk[4 * j4 + 5], x1.y, k1);
                k1 = fmaf(wk[4 * j4 + 6], x1.z, k1); k1 = fmaf(wk[4 * j4 + 7], x1.w, k1);
            }
            Q[ag * 384 + t] = q0 + q1;
            K[ag * 384 + t] = k0 + k1;
        }
    }
}

// ---------------- Pair kernel: filter net + alpha, 4-pair unrolled ----------
__global__ __launch_bounds__(384) void k_pair(
    const float* __restrict__ rbf, const float* __restrict__ phi,
    const float* __restrict__ mask, const int* __restrict__ idx_i,
    const int* __restrict__ idx_j, const float* __restrict__ W_f1,
    const float* __restrict__ b_f1, const float* __restrict__ W_f2,
    const float* __restrict__ b_f2, const float* __restrict__ Q,
    const float* __restrict__ K, float* __restrict__ alpha)
{
    __shared__ float wf1s[32][33];
    __shared__ float b1s[32];
    __shared__ float rbf_s[64][36];
    __shared__ float h1_s[64][36];
    __shared__ float phi_s[64];
    __shared__ float m_s[64];
    __shared__ int   i_s[64];
    __shared__ int   j_s[64];
    __shared__ float alpha_s[64 * 12];

    int t = threadIdx.x;                 // == e = d*128 + h*32 + f
    int p0 = blockIdx.x * 64;
    int dh = t >> 5;                     // d*4+h

    // W_f2 column -> 32 registers
    float wf2r[32];
    #pragma unroll
    for (int k = 0; k < 32; ++k) wf2r[k] = W_f2[k * 384 + t];
    float b2 = b_f2[t];

    for (int idx = t; idx < 1024; idx += 384) wf1s[idx >> 5][idx & 31] = W_f1[idx];
    if (t < 32) b1s[t] = b_f1[t];
    for (int idx = t; idx < 2048; idx += 384) {
        int pp = idx >> 5, l = idx & 31;
        int pg = p0 + pp;
        rbf_s[pp][l] = (pg < N_PAIR) ? rbf[pg * 32 + l] : 0.f;
    }
    if (t < 64) {
        int pg = p0 + t;
        bool v = pg < N_PAIR;
        phi_s[t] = v ? phi[pg] : 0.f;
        m_s[t]   = v ? mask[pg] : 0.f;
        i_s[t]   = v ? idx_i[pg] : 0;
        j_s[t]   = v ? idx_j[pg] : 0;
    }
    __syncthreads();

    // h1 = ssp(rbf @ W_f1 + b_f1)
    for (int idx = t; idx < 2048; idx += 384) {
        int pp = idx >> 5, l = idx & 31;
        float acc = b1s[l];
        #pragma unroll
        for (int k = 0; k < 32; ++k)
            acc = fmaf(rbf_s[pp][k], wf1s[k][l], acc);
        h1_s[pp][l] = sspf(acc);
    }
    __syncthreads();

    // 4 pairs per iteration: 8 gathers in flight, 4 interleaved shuffle chains
    float qc[4], kc[4];
    #pragma unroll
    for (int u = 0; u < 4; ++u) {
        qc[u] = Q[i_s[u] * 384 + t];
        kc[u] = K[j_s[u] * 384 + t];
    }
    for (int pb = 0; pb < 64; pb += 4) {
        float qn[4], kn[4];
        if (pb < 60) {
            #pragma unroll
            for (int u = 0; u < 4; ++u) {
                qn[u] = Q[i_s[pb + 4 + u] * 384 + t];
                kn[u] = K[j_s[pb + 4 + u] * 384 + t];
            }
        }
        float w0[4], w1[4];
        #pragma unroll
        for (int u = 0; u < 4; ++u) { w0[u] = b2; w1[u] = 0.f; }
        #pragma unroll
        for (int k4 = 0; k4 < 8; ++k4) {
            #pragma unroll
            for (int u = 0; u < 4; ++u) {
                float4 hv = *(const float4*)&h1_s[pb + u][k4 * 4];
                if (k4 & 1) {
                    w1[u] = fmaf(hv.x, wf2r[4 * k4 + 0], w1[u]);
                    w1[u] = fmaf(hv.y, wf2r[4 * k4 + 1], w1[u]);
                    w1[u] = fmaf(hv.z, wf2r[4 * k4 + 2], w1[u]);
                    w1[u] = fmaf(hv.w, wf2r[4 * k4 + 3], w1[u]);
                } else {
                    w0[u] = fmaf(hv.x, wf2r[4 * k4 + 0], w0[u]);
                    w0[u] = fmaf(hv.y, wf2r[4 * k4 + 1], w0[u]);
                    w0[u] = fmaf(hv.z, wf2r[4 * k4 + 2], w0[u]);
                    w0[u] = fmaf(hv.w, wf2r[4 * k4 + 3], w0[u]);
                }
            }
        }
        float part[4];
        #pragma unroll
        for (int u = 0; u < 4; ++u)
            part[u] = qc[u] * kc[u] * ((w0[u] + w1[u]) * phi_s[pb + u]);
        #pragma unroll
        for (int off = 16; off >= 1; off >>= 1) {
            #pragma unroll
            for (int u = 0; u < 4; ++u)
                part[u] += __shfl_xor(part[u], off, 32);
        }
        if ((t & 31) == 0) {
            #pragma unroll
            for (int u = 0; u < 4; ++u) {
                float m = m_s[pb + u];
                alpha_s[(pb + u) * 12 + dh] = part[u] * m * m * 0.17677669529663687f;
            }
        }
        if (pb < 60) {
            #pragma unroll
            for (int u = 0; u < 4; ++u) { qc[u] = qn[u]; kc[u] = kn[u]; }
        }
    }
    __syncthreads();
    // coalesced alpha write: 768 floats per block
    #pragma unroll
    for (int r = 0; r < 2; ++r) {
        int idx = t + r * 384;
        int g = p0 * 12 + idx;
        if (g < N_PAIR * 12) alpha[g] = alpha_s[idx];
    }
}

__device__ __forceinline__ int lower_bound_i(const int* __restrict__ arr, int n, int val) {
    int lo = 0, hi = n;
    while (lo < hi) {
        int mid = (lo + hi) >> 1;
        if (arr[mid] < val) lo = mid + 1; else hi = mid;
    }
    return lo;
}

// ---------------- Segment offsets: seg[a] = lower_bound(idx_i, a) -----------
__global__ __launch_bounds__(256) void k_seg(const int* __restrict__ idx_i,
                                             int* __restrict__ seg)
{
    int a = blockIdx.x * 256 + threadIdx.x;
    if (a <= N_ATOMS) seg[a] = lower_bound_i(idx_i, N_PAIR, a);
}

// ---------------- Segment aggregation: 2 pair-groups, prefetched ------------
__global__ __launch_bounds__(256) void k_agg(
    const float* __restrict__ xh, const float* __restrict__ alpha,
    const float* __restrict__ sph, const int* __restrict__ seg,
    const int* __restrict__ idx_j, const float* __restrict__ mask,
    float* __restrict__ agg)
{
    __shared__ float red[15][132];
    int a = blockIdx.x;
    int t = threadIdx.x & 127;
    int grp = threadIdx.x >> 7;          // 0 or 1: alternating pairs
    int h = t >> 5;
    int lo = seg[a], hi = seg[a + 1];

    float acc[15];
    #pragma unroll
    for (int m = 0; m < 15; ++m) acc[m] = 0.f;

    int p = lo + grp;
    float x_cur = 0.f;
    if (p < hi) x_cur = xh[idx_j[p] * 128 + t];
    for (; p < hi; p += 2) {
        int pn = p + 2;
        float x_nxt = 0.f;
        if (pn < hi) x_nxt = xh[idx_j[pn] * 128 + t];
        float xj = x_cur * mask[p];
        float a0v = alpha[p * 12 + h];
        float a1v = alpha[p * 12 + 4 + h];
        float a2v = alpha[p * 12 + 8 + h];
        const float* sp = sph + p * 15;
        #pragma unroll
        for (int m = 0; m < 15; ++m) {
            float al = (m < 3) ? a0v : ((m < 8) ? a1v : a2v);
            acc[m] = fmaf(sp[m] * al, xj, acc[m]);
        }
        x_cur = x_nxt;
    }

    if (grp == 1) {
        #pragma unroll
        for (int m = 0; m < 15; ++m) red[m][t] = acc[m];
    }
    __syncthreads();
    if (grp == 0) {
        #pragma unroll
        for (int m = 0; m < 15; ++m)
            agg[(a * 15 + m) * 128 + t] = acc[m] + red[m][t];
    }
}

extern "C" void kernel_launch(void* const* d_in, const int* in_sizes, int n_in,
                              void* d_out, int out_size, void* d_ws, size_t ws_size,
                              hipStream_t stream) {
    const float* x        = (const float*)d_in[0];
    const float* rbf_ij   = (const float*)d_in[1];
    const float* sph_ij   = (const float*)d_in[2];
    const float* phi_r    = (const float*)d_in[3];
    const int*   idx_i    = (const int*)d_in[4];
    const int*   idx_j    = (const int*)d_in[5];
    const float* pmask    = (const float*)d_in[6];
    const float* W_Q      = (const float*)d_in[7];
    const float* W_K      = (const float*)d_in[8];
    const float* W_in     = (const float*)d_in[9];
    const float* b_in     = (const float*)d_in[10];
    const float* W_f1     = (const float*)d_in[11];
    const float* b_f1     = (const float*)d_in[12];
    const float* W_f2     = (const float*)d_in[13];
    const float* b_f2     = (const float*)d_in[14];
    const float* W_out    = (const float*)d_in[15];
    const float* b_out    = (const float*)d_in[16];
    float* out = (float*)d_out;

    float* ws    = (float*)d_ws;
    float* xh    = ws;                                   // 10000*128
    float* Qbuf  = xh + N_ATOMS * F_DIM;                 // 10000*384
    float* Kbuf  = Qbuf + N_ATOMS * 384;                 // 10000*384
    float* alpha = Kbuf + N_ATOMS * 384;                 // 100000*12
    int*   seg   = (int*)(alpha + N_PAIR * 12);          // 10001 ints

    k_seg<<<(N_ATOMS + 256) / 256, 256, 0, stream>>>(idx_i, seg);
    k_gemm128<<<(N_ATOMS + 127) / 128, 256, 0, stream>>>(x, W_in, b_in, xh, N_ATOMS);
    k_qk<<<(N_ATOMS + 63) / 64, 384, 0, stream>>>(xh, W_Q, W_K, Qbuf, Kbuf);
    k_pair<<<(N_PAIR + 63) / 64, 384, 0, stream>>>(rbf_ij, phi_r, pmask, idx_i, idx_j,
                                                   W_f1, b_f1, W_f2, b_f2, Qbuf, Kbuf, alpha);
    k_agg<<<N_ATOMS, 256, 0, stream>>>(xh, alpha, sph_ij, seg, idx_j, pmask, out);
    k_gemm128<<<(R_OUT + 127) / 128, 256, 0, stream>>>(out, W_out, b_out, out, R_OUT);
}

// Round 4
// 397.795 us; speedup vs baseline: 1.6434x; 1.1607x over previous
//
#include <hip/hip_runtime.h>
#include <hip/hip_bf16.h>

#define N_ATOMS 10000
#define N_PAIR  100000
#define F_DIM   128
#define N_HEAD  4
#define FH      32
#define N_DEG   3
#define M_TOT   15
#define K_RBF   32
#define R_OUT   (N_ATOMS * M_TOT)   // 150000 rows in the output GEMM

typedef __attribute__((ext_vector_type(8))) short short8;   // 8 bf16 = 4 VGPRs
typedef __attribute__((ext_vector_type(4))) float f32x4;

union frag_cast { int i[4]; short8 s; };

__device__ __forceinline__ float sspf(float v) {
    float sp = fmaxf(v, 0.f) + log1pf(expf(-fabsf(v)));
    return sp - 0.69314718055994531f;
}

__device__ __forceinline__ unsigned short bf16_rne(float x) {
    unsigned int u = __float_as_uint(x);
    unsigned int r = u + 0x7fffu + ((u >> 16) & 1u);
    return (unsigned short)(r >> 16);
}
__device__ __forceinline__ float bf16_tof(unsigned short h) {
    return __uint_as_float(((unsigned int)h) << 16);
}

// ---------------- Generic 128-col GEMM (fp32, used for x@W_in only) ---------
__global__ __launch_bounds__(256) void k_gemm128(
    const float* __restrict__ A, const float* __restrict__ B,
    const float* __restrict__ bias, float* __restrict__ C, int rows)
{
    __shared__ float As[32][132];
    __shared__ float Bs[32][132];
    int r0 = blockIdx.x * 128;
    int t = threadIdx.x;
    int ty = t >> 4, tx = t & 15;

    float acc[8][8];
    #pragma unroll
    for (int i = 0; i < 8; ++i)
        #pragma unroll
        for (int j = 0; j < 8; ++j) acc[i][j] = 0.f;

    for (int k0 = 0; k0 < 128; k0 += 32) {
        #pragma unroll
        for (int r = 0; r < 16; ++r) {
            int idx = t + 256 * r;
            int row = idx >> 5, kk = idx & 31;
            int grow = r0 + row;
            As[kk][row] = (grow < rows) ? A[grow * 128 + k0 + kk] : 0.f;
        }
        #pragma unroll
        for (int r = 0; r < 16; ++r) {
            int idx = t + 256 * r;
            int kk = idx >> 7, c = idx & 127;
            Bs[kk][c] = B[(k0 + kk) * 128 + c];
        }
        __syncthreads();

        #pragma unroll
        for (int kk = 0; kk < 32; ++kk) {
            float a[8], b[8];
            *(float4*)&a[0] = *(const float4*)&As[kk][ty * 4];
            *(float4*)&a[4] = *(const float4*)&As[kk][64 + ty * 4];
            *(float4*)&b[0] = *(const float4*)&Bs[kk][tx * 4];
            *(float4*)&b[4] = *(const float4*)&Bs[kk][64 + tx * 4];
            #pragma unroll
            for (int i = 0; i < 8; ++i)
                #pragma unroll
                for (int j = 0; j < 8; ++j)
                    acc[i][j] = fmaf(a[i], b[j], acc[i][j]);
        }
        __syncthreads();
    }

    float bj[8];
    #pragma unroll
    for (int j = 0; j < 4; ++j) { bj[j] = bias[tx * 4 + j]; bj[4 + j] = bias[64 + tx * 4 + j]; }

    #pragma unroll
    for (int i = 0; i < 8; ++i) {
        int row = r0 + ((i < 4) ? (ty * 4 + i) : (64 + ty * 4 + (i - 4)));
        if (row < rows) {
            float4 v0, v1;
            v0.x = acc[i][0] + bj[0]; v0.y = acc[i][1] + bj[1];
            v0.z = acc[i][2] + bj[2]; v0.w = acc[i][3] + bj[3];
            v1.x = acc[i][4] + bj[4]; v1.y = acc[i][5] + bj[5];
            v1.z = acc[i][6] + bj[6]; v1.w = acc[i][7] + bj[7];
            *(float4*)&C[row * 128 + tx * 4] = v0;
            *(float4*)&C[row * 128 + 64 + tx * 4] = v1;
        }
    }
}

// ---------------- Q/K projection: 32 atoms/block (313 blocks) ---------------
__global__ __launch_bounds__(384) void k_qk(
    const float* __restrict__ xh, const float* __restrict__ W_Q,
    const float* __restrict__ W_K, float* __restrict__ Q, float* __restrict__ K)
{
    __shared__ float xfs[32][128];
    int t = threadIdx.x;                 // == e
    int h = (t >> 5) & 3;
    float wq[32], wk[32];
    const float4* wqp = (const float4*)(W_Q + t * 32);
    const float4* wkp = (const float4*)(W_K + t * 32);
    #pragma unroll
    for (int j4 = 0; j4 < 8; ++j4) {
        float4 a = wqp[j4], b = wkp[j4];
        wq[4 * j4 + 0] = a.x; wq[4 * j4 + 1] = a.y; wq[4 * j4 + 2] = a.z; wq[4 * j4 + 3] = a.w;
        wk[4 * j4 + 0] = b.x; wk[4 * j4 + 1] = b.y; wk[4 * j4 + 2] = b.z; wk[4 * j4 + 3] = b.w;
    }
    int ab = blockIdx.x * 32;
    for (int idx = t; idx < 4096; idx += 384) {
        int aa = idx >> 7, f = idx & 127;
        int ag = ab + aa;
        xfs[aa][f] = (ag < N_ATOMS) ? xh[ag * 128 + f] : 0.f;
    }
    __syncthreads();
    for (int aa = 0; aa < 32; ++aa) {
        int ag = ab + aa;
        if (ag >= N_ATOMS) break;
        const float4* xv = (const float4*)&xfs[aa][h * 32];
        float q0 = 0.f, q1 = 0.f, k0 = 0.f, k1 = 0.f;
        #pragma unroll
        for (int j4 = 0; j4 < 8; j4 += 2) {
            float4 x0 = xv[j4], x1 = xv[j4 + 1];
            q0 = fmaf(wq[4 * j4 + 0], x0.x, q0); q0 = fmaf(wq[4 * j4 + 1], x0.y, q0);
            q0 = fmaf(wq[4 * j4 + 2], x0.z, q0); q0 = fmaf(wq[4 * j4 + 3], x0.w, q0);
            q1 = fmaf(wq[4 * j4 + 4], x1.x, q1); q1 = fmaf(wq[4 * j4 + 5], x1.y, q1);
            q1 = fmaf(wq[4 * j4 + 6], x1.z, q1); q1 = fmaf(wq[4 * j4 + 7], x1.w, q1);
            k0 = fmaf(wk[4 * j4 + 0], x0.x, k0); k0 = fmaf(wk[4 * j4 + 1], x0.y, k0);
            k0 = fmaf(wk[4 * j4 + 2], x0.z, k0); k0 = fmaf(wk[4 * j4 + 3], x0.w, k0);
            k1 = fmaf(wk[4 * j4 + 4], x1.x, k1); k1 = fmaf(wk[4 * j4 + 5], x1.y, k1);
            k1 = fmaf(wk[4 * j4 + 6], x1.z, k1); k1 = fmaf(wk[4 * j4 + 7], x1.w, k1);
        }
        Q[ag * 384 + t] = q0 + q1;
        K[ag * 384 + t] = k0 + k1;
    }
}

// ---------------- Pair kernel: 2 e-columns/thread, width-16 reduction -------
__global__ __launch_bounds__(384) void k_pair(
    const float* __restrict__ rbf, const float* __restrict__ phi,
    const float* __restrict__ mask, const int* __restrict__ idx_i,
    const int* __restrict__ idx_j, const float* __restrict__ W_f1,
    const float* __restrict__ b_f1, const float* __restrict__ W_f2,
    const float* __restrict__ b_f2, const float* __restrict__ Q,
    const float* __restrict__ K, float* __restrict__ alpha)
{
    __shared__ float wf1s[32][33];
    __shared__ float b1s[32];
    __shared__ float rbf_s[64][36];
    __shared__ float h1_s[64][36];
    __shared__ float phi_s[64];
    __shared__ float m_s[64];
    __shared__ int   i_s[64];
    __shared__ int   j_s[64];
    __shared__ float alpha_s[64 * 12];

    int t = threadIdx.x;
    int p0 = blockIdx.x * 64;
    int pr = t / 192;            // 0/1, uniform per wave (waves 0-2 vs 3-5)
    int c  = t % 192;
    int dh = c >> 4;             // 0..11
    int f0 = c & 15;
    int e0 = dh * 32 + f0;
    int e1 = e0 + 16;

    // two W_f2 columns in registers
    float wf2a[32], wf2b[32];
    #pragma unroll
    for (int k = 0; k < 32; ++k) {
        wf2a[k] = W_f2[k * 384 + e0];
        wf2b[k] = W_f2[k * 384 + e1];
    }
    float b2a = b_f2[e0], b2b = b_f2[e1];

    for (int idx = t; idx < 1024; idx += 384) wf1s[idx >> 5][idx & 31] = W_f1[idx];
    if (t < 32) b1s[t] = b_f1[t];
    for (int idx = t; idx < 2048; idx += 384) {
        int pp = idx >> 5, l = idx & 31;
        int pg = p0 + pp;
        rbf_s[pp][l] = (pg < N_PAIR) ? rbf[pg * 32 + l] : 0.f;
    }
    if (t < 64) {
        int pg = p0 + t;
        bool v = pg < N_PAIR;
        phi_s[t] = v ? phi[pg] : 0.f;
        m_s[t]   = v ? mask[pg] : 0.f;
        i_s[t]   = v ? idx_i[pg] : 0;
        j_s[t]   = v ? idx_j[pg] : 0;
    }
    __syncthreads();

    for (int idx = t; idx < 2048; idx += 384) {
        int pp = idx >> 5, l = idx & 31;
        float acc = b1s[l];
        #pragma unroll
        for (int k = 0; k < 32; ++k)
            acc = fmaf(rbf_s[pp][k], wf1s[k][l], acc);
        h1_s[pp][l] = sspf(acc);
    }
    __syncthreads();

    // each thread handles 32 pairs (parity pr), 2 pairs per iteration
    float qa0 = Q[i_s[pr] * 384 + e0],     qb0 = Q[i_s[pr] * 384 + e1];
    float ka0 = K[j_s[pr] * 384 + e0],     kb0 = K[j_s[pr] * 384 + e1];
    float qa1 = Q[i_s[pr + 2] * 384 + e0], qb1 = Q[i_s[pr + 2] * 384 + e1];
    float ka1 = K[j_s[pr + 2] * 384 + e0], kb1 = K[j_s[pr + 2] * 384 + e1];

    for (int pb = 0; pb < 64; pb += 4) {
        int pA = pb + pr, pB = pb + 2 + pr;
        float nqa0, nqb0, nka0, nkb0, nqa1, nqb1, nka1, nkb1;
        if (pb < 60) {
            int nA = pA + 4, nB = pB + 4;
            nqa0 = Q[i_s[nA] * 384 + e0]; nqb0 = Q[i_s[nA] * 384 + e1];
            nka0 = K[j_s[nA] * 384 + e0]; nkb0 = K[j_s[nA] * 384 + e1];
            nqa1 = Q[i_s[nB] * 384 + e0]; nqb1 = Q[i_s[nB] * 384 + e1];
            nka1 = K[j_s[nB] * 384 + e0]; nkb1 = K[j_s[nB] * 384 + e1];
        }
        float w00 = b2a, w01 = b2b, w10 = b2a, w11 = b2b;
        #pragma unroll
        for (int k4 = 0; k4 < 8; ++k4) {
            float4 h0 = *(const float4*)&h1_s[pA][k4 * 4];
            float4 h1v = *(const float4*)&h1_s[pB][k4 * 4];
            w00 = fmaf(h0.x, wf2a[4 * k4 + 0], w00); w00 = fmaf(h0.y, wf2a[4 * k4 + 1], w00);
            w00 = fmaf(h0.z, wf2a[4 * k4 + 2], w00); w00 = fmaf(h0.w, wf2a[4 * k4 + 3], w00);
            w01 = fmaf(h0.x, wf2b[4 * k4 + 0], w01); w01 = fmaf(h0.y, wf2b[4 * k4 + 1], w01);
            w01 = fmaf(h0.z, wf2b[4 * k4 + 2], w01); w01 = fmaf(h0.w, wf2b[4 * k4 + 3], w01);
            w10 = fmaf(h1v.x, wf2a[4 * k4 + 0], w10); w10 = fmaf(h1v.y, wf2a[4 * k4 + 1], w10);
            w10 = fmaf(h1v.z, wf2a[4 * k4 + 2], w10); w10 = fmaf(h1v.w, wf2a[4 * k4 + 3], w10);
            w11 = fmaf(h1v.x, wf2b[4 * k4 + 0], w11); w11 = fmaf(h1v.y, wf2b[4 * k4 + 1], w11);
            w11 = fmaf(h1v.z, wf2b[4 * k4 + 2], w11); w11 = fmaf(h1v.w, wf2b[4 * k4 + 3], w11);
        }
        float part0 = (qa0 * ka0 * w00 + qb0 * kb0 * w01) * phi_s[pA];
        float part1 = (qa1 * ka1 * w10 + qb1 * kb1 * w11) * phi_s[pB];
        #pragma unroll
        for (int off = 8; off >= 1; off >>= 1) {
            part0 += __shfl_xor(part0, off, 16);
            part1 += __shfl_xor(part1, off, 16);
        }
        if (f0 == 0) {
            float m0 = m_s[pA], m1 = m_s[pB];
            alpha_s[pA * 12 + dh] = part0 * m0 * m0 * 0.17677669529663687f;
            alpha_s[pB * 12 + dh] = part1 * m1 * m1 * 0.17677669529663687f;
        }
        if (pb < 60) {
            qa0 = nqa0; qb0 = nqb0; ka0 = nka0; kb0 = nkb0;
            qa1 = nqa1; qb1 = nqb1; ka1 = nka1; kb1 = nkb1;
        }
    }
    __syncthreads();
    #pragma unroll
    for (int r = 0; r < 2; ++r) {
        int idx = t + r * 384;
        int g = p0 * 12 + idx;
        if (g < N_PAIR * 12) alpha[g] = alpha_s[idx];
    }
}

__device__ __forceinline__ int lower_bound_i(const int* __restrict__ arr, int n, int val) {
    int lo = 0, hi = n;
    while (lo < hi) {
        int mid = (lo + hi) >> 1;
        if (arr[mid] < val) lo = mid + 1; else hi = mid;
    }
    return lo;
}

__global__ __launch_bounds__(256) void k_seg(const int* __restrict__ idx_i,
                                             int* __restrict__ seg)
{
    int a = blockIdx.x * 256 + threadIdx.x;
    if (a <= N_ATOMS) seg[a] = lower_bound_i(idx_i, N_PAIR, a);
}

// ---------------- W_out -> transposed hi/lo bf16 ----------------------------
__global__ __launch_bounds__(256) void k_cvt_b(
    const float* __restrict__ W, unsigned short* __restrict__ Bth,
    unsigned short* __restrict__ Btl)
{
    int idx = blockIdx.x * 256 + threadIdx.x;   // 16384 total
    int cc = idx >> 7, kk = idx & 127;
    float v = W[kk * 128 + cc];                 // transpose read
    unsigned short h = bf16_rne(v);
    unsigned short l = bf16_rne(v - bf16_tof(h));
    Bth[cc * 128 + kk] = h;
    Btl[cc * 128 + kk] = l;
}

// ---------------- Segment aggregation -> packed hi/lo bf16 into d_out -------
__global__ __launch_bounds__(256) void k_agg(
    const float* __restrict__ xh, const float* __restrict__ alpha,
    const float* __restrict__ sph, const int* __restrict__ seg,
    const int* __restrict__ idx_j, const float* __restrict__ mask,
    unsigned int* __restrict__ aggp)
{
    __shared__ float red[15][132];
    int a = blockIdx.x;
    int t = threadIdx.x & 127;
    int grp = threadIdx.x >> 7;
    int h = t >> 5;
    int lo = seg[a], hi = seg[a + 1];

    float acc[15];
    #pragma unroll
    for (int m = 0; m < 15; ++m) acc[m] = 0.f;

    int p = lo + grp;
    float x_cur = 0.f;
    if (p < hi) x_cur = xh[idx_j[p] * 128 + t];
    for (; p < hi; p += 2) {
        int pn = p + 2;
        float x_nxt = 0.f;
        if (pn < hi) x_nxt = xh[idx_j[pn] * 128 + t];
        float xj = x_cur * mask[p];
        float a0v = alpha[p * 12 + h];
        float a1v = alpha[p * 12 + 4 + h];
        float a2v = alpha[p * 12 + 8 + h];
        const float* sp = sph + p * 15;
        #pragma unroll
        for (int m = 0; m < 15; ++m) {
            float al = (m < 3) ? a0v : ((m < 8) ? a1v : a2v);
            acc[m] = fmaf(sp[m] * al, xj, acc[m]);
        }
        x_cur = x_nxt;
    }

    if (grp == 1) {
        #pragma unroll
        for (int m = 0; m < 15; ++m) red[m][t] = acc[m];
    }
    __syncthreads();
    if (grp == 0) {
        #pragma unroll
        for (int m = 0; m < 15; ++m) {
            float v = acc[m] + red[m][t];
            unsigned short hh = bf16_rne(v);
            unsigned short ll = bf16_rne(v - bf16_tof(hh));
            aggp[(a * 15 + m) * 128 + t] = ((unsigned int)hh << 16) | (unsigned int)ll;
        }
    }
}

// ---------------- out = agg @ W_out + b_out via bf16x3 MFMA -----------------
// Block: 256 threads = 4 waves; each wave owns 32 rows x 128 cols.
// In-place on d_out: A (packed hi/lo) is fully read before any store.
__global__ __launch_bounds__(256) void k_out_mfma(
    const unsigned int* __restrict__ Apack,
    const unsigned short* __restrict__ Bth, const unsigned short* __restrict__ Btl,
    const float* __restrict__ bias, float* __restrict__ C)
{
    int t = threadIdx.x;
    int wave = t >> 6, lane = t & 63;
    int quad = lane >> 4, l15 = lane & 15;
    long rowbase = (long)blockIdx.x * 128 + wave * 32;

    // load + unpack all A fragments: 2 row-tiles x 4 k-steps, hi and lo
    short8 ah[2][4], al[2][4];
    #pragma unroll
    for (int rt = 0; rt < 2; ++rt) {
        long row = rowbase + rt * 16 + l15;
        if (row > R_OUT - 1) row = R_OUT - 1;
        #pragma unroll
        for (int ks = 0; ks < 4; ++ks) {
            const uint4* ap = (const uint4*)(Apack + row * 128 + ks * 32 + quad * 8);
            uint4 u01 = ap[0], u23 = ap[1];
            unsigned int u[8] = {u01.x, u01.y, u01.z, u01.w, u23.x, u23.y, u23.z, u23.w};
            frag_cast fh, fl;
            #pragma unroll
            for (int q = 0; q < 4; ++q) {
                unsigned int a0 = u[2 * q], a1 = u[2 * q + 1];
                fh.i[q] = (int)((a0 >> 16) | (a1 & 0xffff0000u));
                fl.i[q] = (int)((a0 & 0xffffu) | (a1 << 16));
            }
            ah[rt][ks] = fh.s;
            al[rt][ks] = fl.s;
        }
    }

    // loop over 8 column tiles
    #pragma unroll 2
    for (int nt = 0; nt < 8; ++nt) {
        int colbase = nt * 16;
        short8 bh[4], bl[4];
        #pragma unroll
        for (int ks = 0; ks < 4; ++ks) {
            int off = (colbase + l15) * 128 + ks * 32 + quad * 8;
            bh[ks] = *(const short8*)(Bth + off);
            bl[ks] = *(const short8*)(Btl + off);
        }
        f32x4 acc0 = {0.f, 0.f, 0.f, 0.f};
        f32x4 acc1 = {0.f, 0.f, 0.f, 0.f};
        #pragma unroll
        for (int ks = 0; ks < 4; ++ks) {
            acc0 = __builtin_amdgcn_mfma_f32_16x16x32_bf16(ah[0][ks], bh[ks], acc0, 0, 0, 0);
            acc1 = __builtin_amdgcn_mfma_f32_16x16x32_bf16(ah[1][ks], bh[ks], acc1, 0, 0, 0);
            acc0 = __builtin_amdgcn_mfma_f32_16x16x32_bf16(al[0][ks], bh[ks], acc0, 0, 0, 0);
            acc1 = __builtin_amdgcn_mfma_f32_16x16x32_bf16(al[1][ks], bh[ks], acc1, 0, 0, 0);
            acc0 = __builtin_amdgcn_mfma_f32_16x16x32_bf16(ah[0][ks], bl[ks], acc0, 0, 0, 0);
            acc1 = __builtin_amdgcn_mfma_f32_16x16x32_bf16(ah[1][ks], bl[ks], acc1, 0, 0, 0);
        }
        float bv = bias[colbase + l15];
        #pragma unroll
        for (int r = 0; r < 4; ++r) {
            long row0 = rowbase + quad * 4 + r;
            long row1 = rowbase + 16 + quad * 4 + r;
            if (row0 < R_OUT) C[row0 * 128 + colbase + l15] = acc0[r] + bv;
            if (row1 < R_OUT) C[row1 * 128 + colbase + l15] = acc1[r] + bv;
        }
    }
}

extern "C" void kernel_launch(void* const* d_in, const int* in_sizes, int n_in,
                              void* d_out, int out_size, void* d_ws, size_t ws_size,
                              hipStream_t stream) {
    const float* x        = (const float*)d_in[0];
    const float* rbf_ij   = (const float*)d_in[1];
    const float* sph_ij   = (const float*)d_in[2];
    const float* phi_r    = (const float*)d_in[3];
    const int*   idx_i    = (const int*)d_in[4];
    const int*   idx_j    = (const int*)d_in[5];
    const float* pmask    = (const float*)d_in[6];
    const float* W_Q      = (const float*)d_in[7];
    const float* W_K      = (const float*)d_in[8];
    const float* W_in     = (const float*)d_in[9];
    const float* b_in     = (const float*)d_in[10];
    const float* W_f1     = (const float*)d_in[11];
    const float* b_f1     = (const float*)d_in[12];
    const float* W_f2     = (const float*)d_in[13];
    const float* b_f2     = (const float*)d_in[14];
    const float* W_out    = (const float*)d_in[15];
    const float* b_out    = (const float*)d_in[16];
    float* out = (float*)d_out;

    float* ws    = (float*)d_ws;
    float* xh    = ws;                                   // 10000*128
    float* Qbuf  = xh + N_ATOMS * F_DIM;                 // 10000*384
    float* Kbuf  = Qbuf + N_ATOMS * 384;                 // 10000*384
    float* alpha = Kbuf + N_ATOMS * 384;                 // 100000*12
    int*   seg   = (int*)(alpha + N_PAIR * 12);          // 10001 ints
    unsigned short* Bth = (unsigned short*)(seg + 10432); // 16384 bf16
    unsigned short* Btl = Bth + 16384;                    // 16384 bf16

    k_seg<<<(N_ATOMS + 256) / 256, 256, 0, stream>>>(idx_i, seg);
    k_cvt_b<<<64, 256, 0, stream>>>(W_out, Bth, Btl);
    k_gemm128<<<(N_ATOMS + 127) / 128, 256, 0, stream>>>(x, W_in, b_in, xh, N_ATOMS);
    k_qk<<<(N_ATOMS + 31) / 32, 384, 0, stream>>>(xh, W_Q, W_K, Qbuf, Kbuf);
    k_pair<<<(N_PAIR + 63) / 64, 384, 0, stream>>>(rbf_ij, phi_r, pmask, idx_i, idx_j,
                                                   W_f1, b_f1, W_f2, b_f2, Qbuf, Kbuf, alpha);
    k_agg<<<N_ATOMS, 256, 0, stream>>>(xh, alpha, sph_ij, seg, idx_j, pmask,
                                       (unsigned int*)d_out);
    k_out_mfma<<<(R_OUT + 127) / 128, 256, 0, stream>>>((const unsigned int*)d_out,
                                                        Bth, Btl, b_out, out);
}